// Round 2
// baseline (619.678 us; speedup 1.0000x reference)
//
#include <hip/hip_runtime.h>
#include <stdint.h>

typedef __bf16 bf16;
typedef __bf16 bf16x8 __attribute__((ext_vector_type(8)));
typedef float f32x4 __attribute__((ext_vector_type(4)));

enum { EPI_STORE = 0, EPI_BIAS_RELU = 1, EPI_VRED = 2 };

__device__ __forceinline__ void load_lds16(const bf16* g, bf16* l) {
  __builtin_amdgcn_global_load_lds((const __attribute__((address_space(1))) void*)g,
                                   (__attribute__((address_space(3))) void*)l, 16, 0, 0);
}

// C[M,N] = A[M,K] @ B[K,N], B supplied transposed (Bt[N,K]). All bf16, k-contiguous.
// Tile BM=64 x BN=256 x BK=32, 256 threads = 4 waves, wave tile 32x128.
// Staging via global_load_lds dwordx4 (no VGPR round-trip).
template<int EPI>
__global__ __launch_bounds__(256, 3)
void gemm_bt(const bf16* __restrict__ Ap, const bf16* __restrict__ Btp,
             const float* __restrict__ bias, bf16* __restrict__ C,
             float* __restrict__ vpart, const bf16* __restrict__ a0p,
             int K, int ldA, int ldBt, int ldC,
             long sA, long sBt, long sC)
{
  constexpr int BM = 64, BN = 256, BK = 32;
  __shared__ __align__(16) bf16 As[BM * BK];   // 4 KB, [m][k]
  __shared__ __align__(16) bf16 Bs[BN * BK];   // 16 KB, [n][k]
  __shared__ float a0s[BM];
  __shared__ float vsum[BN];

  const int tid  = threadIdx.x;
  const int lane = tid & 63;
  const int wid  = tid >> 6;
  const int wm   = wid & 1;    // m half (32 rows)
  const int wn   = wid >> 1;   // n half (128 cols)
  const int l15  = lane & 15;
  const int quad = lane >> 4;

  const int nb = blockIdx.x, mb = blockIdx.y, g = blockIdx.z;

  // per-thread staging source pointers: row = tid>>2, k-chunk = (tid&3)*8
  const bf16* Ag = Ap + (long)g * sA + (long)(mb * BM + (tid >> 2)) * ldA + (tid & 3) * 8;
  const bf16* Bg = Btp + (long)g * sBt + (long)(nb * BN + (tid >> 2)) * ldBt + (tid & 3) * 8;
  const long bstep = (long)64 * ldBt;

  if constexpr (EPI == EPI_VRED) {
    if (tid < BM) a0s[tid] = (float)a0p[(long)g * sA + mb * BM + tid];  // adj[g][0][row]
    vsum[tid] = 0.f;
  }

  f32x4 acc[2][8] = {};

  for (int ks = 0; ks < K; ks += BK) {
    __syncthreads();
    load_lds16(Ag + ks, As + tid * 8);
    #pragma unroll
    for (int p = 0; p < 4; ++p)
      load_lds16(Bg + p * bstep + ks, Bs + p * 2048 + tid * 8);
    __syncthreads();

    bf16x8 af[2], bfr[8];
    #pragma unroll
    for (int i = 0; i < 2; ++i)
      af[i] = *(const bf16x8*)&As[(wm * 32 + i * 16 + l15) * BK + quad * 8];
    #pragma unroll
    for (int j = 0; j < 8; ++j)
      bfr[j] = *(const bf16x8*)&Bs[(wn * 128 + j * 16 + l15) * BK + quad * 8];
    #pragma unroll
    for (int i = 0; i < 2; ++i)
      #pragma unroll
      for (int j = 0; j < 8; ++j)
        acc[i][j] = __builtin_amdgcn_mfma_f32_16x16x32_bf16(af[i], bfr[j], acc[i][j], 0, 0, 0);
  }

  if constexpr (EPI == EPI_STORE || EPI == EPI_BIAS_RELU) {
    bf16* Cg = C + (long)g * sC;
    #pragma unroll
    for (int i = 0; i < 2; ++i) {
      const int row0 = mb * BM + wm * 32 + i * 16 + quad * 4;
      #pragma unroll
      for (int j = 0; j < 8; ++j) {
        const int col = nb * BN + wn * 128 + j * 16 + l15;
        float bv = 0.f;
        if constexpr (EPI == EPI_BIAS_RELU) bv = bias[col];
        #pragma unroll
        for (int rr = 0; rr < 4; ++rr) {
          float v = acc[i][j][rr];
          if constexpr (EPI == EPI_BIAS_RELU) v = fmaxf(v + bv, 0.f);
          Cg[(long)(row0 + rr) * ldC + col] = (bf16)v;
        }
      }
    }
  } else {  // EPI_VRED
    __syncthreads();
    #pragma unroll
    for (int j = 0; j < 8; ++j) {
      const int col = wn * 128 + j * 16 + l15;
      const float bv = bias[col];
      float p = 0.f;
      #pragma unroll
      for (int i = 0; i < 2; ++i) {
        const int lr = wm * 32 + i * 16 + quad * 4;
        #pragma unroll
        for (int rr = 0; rr < 4; ++rr)
          p += fmaxf(acc[i][j][rr] + bv, 0.f) * a0s[lr + rr];
      }
      atomicAdd(&vsum[col], p);
    }
    __syncthreads();
    vpart[((long)g * 16 + mb) * 256 + tid] = vsum[tid];
  }
}

// Convert adj (67.1M f32) and embs (8.4M f32) to bf16. One 8-elem chunk/thread.
__global__ void cvt_prep(const float* __restrict__ adj, const float* __restrict__ embs,
                         bf16* __restrict__ adjb, bf16* __restrict__ embsb)
{
  const long c = (long)blockIdx.x * 256 + threadIdx.x;   // 0 .. 9437183
  const float* src; bf16* dst; long off;
  if (c < 8388608) { src = adj;  dst = adjb;  off = c * 8; }
  else             { src = embs; dst = embsb; off = (c - 8388608) * 8; }
  float4 v0 = *(const float4*)(src + off);
  float4 v1 = *(const float4*)(src + off + 4);
  bf16x8 w;
  w[0]=(bf16)v0.x; w[1]=(bf16)v0.y; w[2]=(bf16)v0.z; w[3]=(bf16)v0.w;
  w[4]=(bf16)v1.x; w[5]=(bf16)v1.y; w[6]=(bf16)v1.z; w[7]=(bf16)v1.w;
  *(bf16x8*)(dst + off) = w;
}

// Transpose + convert weights: W0t[h][k]=W0[k][h] (256x128), W1t[h][k]=W1[k][h] (256x256)
__global__ void prep_w(const float* __restrict__ W0, const float* __restrict__ W1,
                       bf16* __restrict__ W0t, bf16* __restrict__ W1t)
{
  const int idx = blockIdx.x * 256 + threadIdx.x;  // 0..65535
  if (idx < 256 * 128) {
    const int h = idx >> 7, k = idx & 127;
    W0t[idx] = (bf16)W0[k * 256 + h];
  }
  const int h = idx >> 8, k = idx & 255;
  W1t[idx] = (bf16)W1[k * 256 + h];
}

// Per graph: v = sum of 16 partials; h3 = relu(v@W2 + b2); out = h3@Wl + bl (fp32)
__global__ void finish_k(const float* __restrict__ vpart, const float* __restrict__ W2,
                         const float* __restrict__ b2, const float* __restrict__ Wl,
                         const float* __restrict__ bl, float* __restrict__ out)
{
  const int b = blockIdx.x, t = threadIdx.x;
  __shared__ float v[256], h3[256];
  float s = 0.f;
  #pragma unroll
  for (int mb = 0; mb < 16; ++mb) s += vpart[((long)b * 16 + mb) * 256 + t];
  v[t] = s;
  __syncthreads();
  float z = b2[t];
  for (int k = 0; k < 256; ++k) z += v[k] * W2[k * 256 + t];
  h3[t] = fmaxf(z, 0.f);
  __syncthreads();
  if (t < 128) {
    float o = bl[t];
    for (int h = 0; h < 256; ++h) o += h3[h] * Wl[h * 128 + t];
    out[(long)b * 128 + t] = o;
  }
}

extern "C" void kernel_launch(void* const* d_in, const int* in_sizes, int n_in,
                              void* d_out, int out_size, void* d_ws, size_t ws_size,
                              hipStream_t stream) {
  const float* embs = (const float*)d_in[0];  // [64,1024,128]
  const float* adj  = (const float*)d_in[1];  // [64,1024,1024]
  const float* W0   = (const float*)d_in[2];  // [128,256]
  const float* b0   = (const float*)d_in[3];
  const float* W1   = (const float*)d_in[4];  // [256,256]
  const float* b1   = (const float*)d_in[5];
  const float* W2   = (const float*)d_in[6];  // [256,256]
  const float* b2   = (const float*)d_in[7];
  const float* Wl   = (const float*)d_in[8];  // [256,128]
  const float* bl   = (const float*)d_in[9];
  float* out = (float*)d_out;

  char* ws = (char*)d_ws;
  bf16*  adjb  = (bf16*)(ws);                   // 134217728 B
  bf16*  embsb = (bf16*)(ws + 134217728);       // 16777216 B
  bf16*  Zt    = (bf16*)(ws + 150994944);       // [64][256][1024] (Z0t then Z1t)
  bf16*  Hb    = (bf16*)(ws + 184549376);       // [64][1024][256]
  bf16*  W0t   = (bf16*)(ws + 218103808);       // [256][128]
  bf16*  W1t   = (bf16*)(ws + 218169344);       // [256][256]
  float* vpart = (float*)(ws + 218300416);      // [64][16][256] f32

  cvt_prep<<<36864, 256, 0, stream>>>(adj, embs, adjb, embsb);
  prep_w<<<256, 256, 0, stream>>>(W0, W1, W0t, W1t);

  // Z0t[h,n] = sum_k W0t[h,k]*embsb[n,k] : M=256,N=1024,K=128
  gemm_bt<EPI_STORE><<<dim3(4, 4, 64), 256, 0, stream>>>(
      W0t, embsb, nullptr, Zt, nullptr, nullptr,
      128, 128, 128, 1024, 0L, 131072L, 262144L);

  // H1[n,h] = relu(sum_m adjb[n,m]*Z0t[h,m] + b0[h]) : M=1024,N=256,K=1024
  gemm_bt<EPI_BIAS_RELU><<<dim3(1, 16, 64), 256, 0, stream>>>(
      adjb, Zt, b0, Hb, nullptr, nullptr,
      1024, 1024, 1024, 256, 1048576L, 262144L, 262144L);

  // Z1t[h,n] = sum_k W1t[h,k]*H1[n,k] : M=256,N=1024,K=256
  gemm_bt<EPI_STORE><<<dim3(4, 4, 64), 256, 0, stream>>>(
      W1t, Hb, nullptr, Zt, nullptr, nullptr,
      256, 256, 256, 1024, 0L, 262144L, 262144L);

  // vpart[g,mb,h] = sum_{rows in mb} adj0[row]*relu((adjb@Z1t)[row,h] + b1[h])
  gemm_bt<EPI_VRED><<<dim3(1, 16, 64), 256, 0, stream>>>(
      adjb, Zt, b1, nullptr, vpart, adjb,
      1024, 1024, 1024, 256, 1048576L, 262144L, 0L);

  finish_k<<<64, 256, 0, stream>>>(vpart, W2, b2, Wl, bl, out);
}